// Round 2
// baseline (295.664 us; speedup 1.0000x reference)
//
#include <hip/hip_runtime.h>
#include <stdint.h>

#define SEQ 1024
#define NB  1024
#define HD  64
#define BH  (NB*HD)            // 65536 elements per timestep plane
#define ROWS_PER_BLK 8

typedef _Float16 f16x8 __attribute__((ext_vector_type(8)));
typedef float    f32x4 __attribute__((ext_vector_type(4)));

// byte offset of 16B slot s within a 1KB region, XOR-swizzled for bank spread
__device__ __forceinline__ int swzb(int s) {
    return (s * 16) ^ (((s >> 3) & 7) << 4);
}
__device__ __forceinline__ uint32_t pkrtz(float a, float b) {
    auto h = __builtin_amdgcn_cvt_pkrtz(a, b);   // v_cvt_pkrtz_f16_f32 -> __fp16x2
    return __builtin_bit_cast(uint32_t, h);
}
__device__ __forceinline__ float fast_tanh(float a) {
    // tanh(a) = 1 - 2/(exp2(a*2*log2e)+1); exact at +-inf, ~2ulp elsewhere
    float e = __builtin_amdgcn_exp2f(a * 2.8853900817779268f);
    return 1.0f - 2.0f * __builtin_amdgcn_rcpf(e + 1.0f);
}

__global__ __launch_bounds__(256) void rnn_kernel(
    const float* __restrict__ x,  const float* __restrict__ h0,
    const float* __restrict__ Wx, const float* __restrict__ bx,
    const float* __restrict__ Wh, const float* __restrict__ bh,
    float* __restrict__ out)
{
    // [dbuf][region: hK0,hK1,xK0,xK1][256 dwords = 1KB]
    __shared__ uint32_t lds[2][4][256];

    const int tid  = threadIdx.x;
    const int w    = tid >> 6;        // wave 0..3: owns output channels [16w,16w+16)
    const int lane = tid & 63;
    const int g    = lane >> 4;       // 16-lane group 0..3
    const int n    = lane & 15;       // MFMA col = batch row in block (valid < 8)
    const int R0   = blockIdx.x * ROWS_PER_BLK;

    // ---- producer mapping: 256 threads cooperatively stage one step's x (2KB) ----
    const int pT = tid >> 7;          // k-tile 0/1
    const int pr = tid & 127;
    const int pg = pr >> 5;           // lane-group of consumer
    const int pn = (pr >> 2) & 7;     // batch row 0..7
    const int pq = pr & 3;            // dword within fragment
    const int k0 = pT * 32 + pg * 8 + pq * 2;
    const int pdw = (swzb(pg * 16 + pn) >> 2) + pq;
    const float* xprod = x + (size_t)(R0 + pn) * HD + k0;

    // consumer fragment read position (16B chunk)
    const int rdw = swzb(lane) >> 2;

    // ---- h-fragment scatter mapping (C-layout -> next-step B-frag slot) ----
    // lane holds C rows j = 16w + 4g + r (r=0..3), col = n. k-pair (j0,j0+1):
    // tile = w>>1, owner group = 2*(w&1)+(g>>1), dword = 2*(g&1)
    const int hTw = w >> 1;
    const int hdw = (swzb((2 * (w & 1) + (g >> 1)) * 16 + n) >> 2) + 2 * (g & 1);

    // ---- weights: A-fragments, resident in VGPRs (RTNE convert) ----
    const int jrow = 16 * w + n;      // A row = lane&15
    f16x8 whA[2], wxA[2];
    {
        const float* wr = Wh + (size_t)jrow * HD;
        const float* xr = Wx + (size_t)jrow * HD;
        #pragma unroll
        for (int T = 0; T < 2; ++T) {
            f16x8 aw, ax;
            #pragma unroll
            for (int e = 0; e < 8; ++e) {
                aw[e] = (_Float16)wr[T * 32 + g * 8 + e];
                ax[e] = (_Float16)xr[T * 32 + g * 8 + e];
            }
            whA[T] = aw; wxA[T] = ax;
        }
    }
    // ---- combined bias as C-init fragment: reg r <-> j = 16w+4g+r ----
    f32x4 bias;
    {
        const int j4 = 16 * w + 4 * g;
        #pragma unroll
        for (int r = 0; r < 4; ++r) bias[r] = bh[j4 + r] + bx[j4 + r];
    }

    // ---- zero LDS (garbage cols n>=8 read zeros -> no NaNs) ----
    {
        int4 z = {0, 0, 0, 0};
        ((int4*)lds)[tid]       = z;
        ((int4*)lds)[tid + 256] = z;
    }
    __syncthreads();

    // ---- stage h_init and x(0) fragments into buf 0 ----
    {
        float2 hv = *(const float2*)(h0 + (size_t)(R0 + pn) * HD + k0);
        lds[0][pT][pdw] = pkrtz(hv.x, hv.y);
        float2 xv = *(const float2*)(xprod);
        lds[0][2 + pT][pdw] = pkrtz(xv.x, xv.y);
    }
    // register ring prefetch: x(1..4)
    float2 r1 = *(const float2*)(xprod + (size_t)1 * BH);
    float2 r2 = *(const float2*)(xprod + (size_t)2 * BH);
    float2 r3 = *(const float2*)(xprod + (size_t)3 * BH);
    float2 r0 = *(const float2*)(xprod + (size_t)4 * BH);
    __syncthreads();

    f16x8 fh0, fh1, fx0, fx1;
    fh0 = __builtin_bit_cast(f16x8, *(const int4*)&lds[0][0][rdw]);
    fh1 = __builtin_bit_cast(f16x8, *(const int4*)&lds[0][1][rdw]);
    fx0 = __builtin_bit_cast(f16x8, *(const int4*)&lds[0][2][rdw]);
    fx1 = __builtin_bit_cast(f16x8, *(const int4*)&lds[0][3][rdw]);

    float* outlast = out + (size_t)SEQ * BH;

    auto STEP = [&](int t, float2& rn) {
        // C^T(j,n) = Wx*x^T + Wh*h^T + bias   (4x mfma 16x16x32 f16)
        f32x4 acc;
        acc = __builtin_amdgcn_mfma_f32_16x16x32_f16(wxA[0], fx0, bias, 0, 0, 0);
        acc = __builtin_amdgcn_mfma_f32_16x16x32_f16(wxA[1], fx1, acc,  0, 0, 0);
        acc = __builtin_amdgcn_mfma_f32_16x16x32_f16(whA[0], fh0, acc,  0, 0, 0);
        acc = __builtin_amdgcn_mfma_f32_16x16x32_f16(whA[1], fh1, acc,  0, 0, 0);

        const int b2 = (t + 1) & 1;
        if (t < SEQ - 1) {
            lds[b2][2 + pT][pdw] = pkrtz(rn.x, rn.y);   // stage x-frag(t+1)
        }
        {   // refill ring with x(t+5) (clamped; tail loads are harmless)
            int tl = t + 5; if (tl > SEQ - 1) tl = SEQ - 1;
            rn = *(const float2*)(xprod + (size_t)tl * BH);
        }

        float hv0 = fast_tanh(acc[0]);
        float hv1 = fast_tanh(acc[1]);
        float hv2 = fast_tanh(acc[2]);
        float hv3 = fast_tanh(acc[3]);

        if (t < SEQ - 1) {
            uint32_t e0 = pkrtz(hv0, hv1);
            uint32_t e1 = pkrtz(hv2, hv3);
            *(int2*)&lds[b2][hTw][hdw] = make_int2((int)e0, (int)e1);
            __syncthreads();
            fh0 = __builtin_bit_cast(f16x8, *(const int4*)&lds[b2][0][rdw]);
            fh1 = __builtin_bit_cast(f16x8, *(const int4*)&lds[b2][1][rdw]);
            fx0 = __builtin_bit_cast(f16x8, *(const int4*)&lds[b2][2][rdw]);
            fx1 = __builtin_bit_cast(f16x8, *(const int4*)&lds[b2][3][rdw]);
        }
        // store after the frag reads so the global store fills LDS latency
        if (n < 8) {
            float4 v = make_float4(hv0, hv1, hv2, hv3);
            float* dst = out + (size_t)t * BH + (size_t)(R0 + n) * HD + 16 * w + 4 * g;
            *(float4*)dst = v;
            if (t == SEQ - 1) {
                *(float4*)(outlast + (size_t)(R0 + n) * HD + 16 * w + 4 * g) = v;
            }
        }
    };

    for (int tb = 0; tb < SEQ; tb += 4) {
        STEP(tb + 0, r1);
        STEP(tb + 1, r2);
        STEP(tb + 2, r3);
        STEP(tb + 3, r0);
    }
}

extern "C" void kernel_launch(void* const* d_in, const int* in_sizes, int n_in,
                              void* d_out, int out_size, void* d_ws, size_t ws_size,
                              hipStream_t stream) {
    const float* x  = (const float*)d_in[0];
    const float* h  = (const float*)d_in[1];
    const float* Wx = (const float*)d_in[2];
    const float* bx = (const float*)d_in[3];
    const float* Wh = (const float*)d_in[4];
    const float* bh = (const float*)d_in[5];
    float* out = (float*)d_out;

    rnn_kernel<<<dim3(NB / ROWS_PER_BLK), dim3(256), 0, stream>>>(x, h, Wx, bx, Wh, bh, out);
}